// Round 1
// baseline (191.682 us; speedup 1.0000x reference)
//
#include <hip/hip_runtime.h>
#include <cmath>
#include <complex>

// ---------------------------------------------------------------------------
// Wigner-3j (real basis, e3nn convention) computed on HOST in double precision,
// exactly replicating the reference's _su2_cg / _q_real_to_complex / _w3j.
// Path weight sqrt(2*l3+1) is folded into each tensor.
// Packed into a struct passed BY VALUE as a kernel argument (2460 bytes).
// ---------------------------------------------------------------------------

struct W3JPack {
    float c000[1];    // (0,0,0) 1*1*1
    float c011[9];    // (0,1,1) 1*3*3
    float c022[25];   // (0,2,2) 1*5*5
    float c101[9];    // (1,0,1) 3*1*3
    float c110[9];    // (1,1,0) 3*3*1
    float c111[27];   // (1,1,1)
    float c112[45];   // (1,1,2)
    float c121[45];   // (1,2,1)
    float c122[75];   // (1,2,2)
    float c202[25];   // (2,0,2)
    float c211[45];   // (2,1,1)
    float c212[75];   // (2,1,2)
    float c220[25];   // (2,2,0)
    float c221[75];   // (2,2,1)
    float c222[125];  // (2,2,2)
};

namespace {

using cd = std::complex<double>;

double factd(int n) { double r = 1.0; for (int i = 2; i <= n; ++i) r *= i; return r; }

double su2_cg(int j1, int j2, int j3, int m1, int m2, int m3) {
    if (m3 != m1 + m2) return 0.0;
    double pref = std::sqrt((2.0 * j3 + 1.0) * factd(j3 + j1 - j2) * factd(j3 - j1 + j2)
                            * factd(j1 + j2 - j3) / factd(j1 + j2 + j3 + 1));
    pref *= std::sqrt(factd(j3 + m3) * factd(j3 - m3) * factd(j1 - m1)
                      * factd(j1 + m1) * factd(j2 - m2) * factd(j2 + m2));
    int kmin = 0;
    if (j2 - j3 - m1 > kmin) kmin = j2 - j3 - m1;
    if (j1 - j3 + m2 > kmin) kmin = j1 - j3 + m2;
    int kmax = j1 + j2 - j3;
    if (j1 - m1 < kmax) kmax = j1 - m1;
    if (j2 + m2 < kmax) kmax = j2 + m2;
    double s = 0.0;
    for (int k = kmin; k <= kmax; ++k) {
        double den = factd(k) * factd(j1 + j2 - j3 - k) * factd(j1 - m1 - k)
                   * factd(j2 + m2 - k) * factd(j3 - j2 + m1 + k) * factd(j3 - j1 - m2 + k);
        s += ((k & 1) ? -1.0 : 1.0) / den;
    }
    return pref * s;
}

void qmat(int l, cd q[5][5]) {
    for (int a = 0; a < 5; ++a) for (int b = 0; b < 5; ++b) q[a][b] = cd(0, 0);
    const double is2 = 1.0 / std::sqrt(2.0);
    for (int m = -l; m < 0; ++m) {
        q[l + m][l - m] = cd(is2, 0.0);   // col l+|m|
        q[l + m][l + m] = cd(0.0, -is2);  // col l-|m|
    }
    q[l][l] = cd(1.0, 0.0);
    for (int m = 1; m <= l; ++m) {
        double sgn = (m & 1) ? -1.0 : 1.0;
        q[l + m][l + m] = cd(sgn * is2, 0.0);
        q[l + m][l - m] = cd(0.0, sgn * is2);
    }
    cd f(1.0, 0.0);
    const cd mi(0.0, -1.0);
    for (int k = 0; k < l; ++k) f *= mi;  // (-i)^l
    for (int a = 0; a < 5; ++a) for (int b = 0; b < 5; ++b) q[a][b] *= f;
}

void w3j_real(int l1, int l2, int l3, float* out, double pw) {
    const int d1 = 2 * l1 + 1, d2 = 2 * l2 + 1, d3 = 2 * l3 + 1;
    cd Q1[5][5], Q2[5][5], Q3[5][5];
    qmat(l1, Q1); qmat(l2, Q2); qmat(l3, Q3);
    double tmp[125];
    double norm2 = 0.0;
    for (int a = 0; a < d1; ++a)
        for (int b = 0; b < d2; ++b)
            for (int c = 0; c < d3; ++c) {
                cd acc(0.0, 0.0);
                for (int i = 0; i < d1; ++i) {
                    int m1 = i - l1;
                    for (int k = 0; k < d2; ++k) {
                        int m2 = k - l2;
                        int m3 = m1 + m2;
                        if (m3 < -l3 || m3 > l3) continue;
                        double cg = su2_cg(l1, l2, l3, m1, m2, m3);
                        if (cg == 0.0) continue;
                        acc += Q1[i][a] * Q2[k][b] * std::conj(Q3[m3 + l3][c]) * cg;
                    }
                }
                double v = acc.real();
                tmp[(a * d2 + b) * d3 + c] = v;
                norm2 += v * v;
            }
    const double scale = pw / std::sqrt(norm2);
    for (int idx = 0; idx < d1 * d2 * d3; ++idx) out[idx] = (float)(tmp[idx] * scale);
}

W3JPack build_pack() {
    W3JPack p;
    const double s3 = std::sqrt(3.0), s5 = std::sqrt(5.0);
    w3j_real(0, 0, 0, p.c000, 1.0);
    w3j_real(0, 1, 1, p.c011, s3);
    w3j_real(0, 2, 2, p.c022, s5);
    w3j_real(1, 0, 1, p.c101, s3);
    w3j_real(1, 1, 0, p.c110, 1.0);
    w3j_real(1, 1, 1, p.c111, s3);
    w3j_real(1, 1, 2, p.c112, s5);
    w3j_real(1, 2, 1, p.c121, s3);
    w3j_real(1, 2, 2, p.c122, s5);
    w3j_real(2, 0, 2, p.c202, s5);
    w3j_real(2, 1, 1, p.c211, s3);
    w3j_real(2, 1, 2, p.c212, s5);
    w3j_real(2, 2, 0, p.c220, 1.0);
    w3j_real(2, 2, 1, p.c221, s3);
    w3j_real(2, 2, 2, p.c222, s5);
    return p;
}

const W3JPack g_pack = build_pack();  // static init at library load; pure constants

} // namespace

// ---------------------------------------------------------------------------
// Kernel: one thread per (mul-block, u, row) task.
//   block0: l1=0, mul1=128 -> Z*128 tasks (waves never straddle task types:
//   block1: l1=1, mul1=64  -> Z*64 tasks    all boundaries are multiples of 64)
//   block2: l1=2, mul1=32  -> Z*32 tasks
// ---------------------------------------------------------------------------

__global__ __launch_bounds__(256) void dtp_kernel(
    const float* __restrict__ x, const float* __restrict__ y,
    const float* __restrict__ w, float* __restrict__ out,
    const W3JPack P, int Z)
{
    const int t = blockIdx.x * 256 + threadIdx.x;
    const int N0 = Z * 128;
    const int N1 = Z * 64;

    if (t < N0) {
        // ----- l1 = 0 block: instrs (0,0,0),(0,1,1),(0,2,2) -----
        const int z = t >> 7, u = t & 127;
        const float* xz = x + (size_t)z * 480;
        const float* yz = y + (size_t)z * 9;
        const float* wz = w + (size_t)z * 960;
        float* oz = out + (size_t)z * 3136;

        const float xv = xz[u];
        const float y0 = yz[0];
        float y1[3], y2[5];
#pragma unroll
        for (int j = 0; j < 3; ++j) y1[j] = yz[1 + j];
#pragma unroll
        for (int j = 0; j < 5; ++j) y2[j] = yz[4 + j];

        // (0,0,0) -> out[0 + u], w[0+u]
        oz[u] = wz[u] * (P.c000[0] * xv * y0);
        // (0,1,1) -> out[128 + 3u + k], w[128+u]
        {
            const float wx = wz[128 + u] * xv;
#pragma unroll
            for (int k = 0; k < 3; ++k) {
                float s = 0.f;
#pragma unroll
                for (int j = 0; j < 3; ++j) s += P.c011[j * 3 + k] * y1[j];
                oz[128 + 3 * u + k] = wx * s;
            }
        }
        // (0,2,2) -> out[512 + 5u + k], w[256+u]
        {
            const float wx = wz[256 + u] * xv;
#pragma unroll
            for (int k = 0; k < 5; ++k) {
                float s = 0.f;
#pragma unroll
                for (int j = 0; j < 5; ++j) s += P.c022[j * 5 + k] * y2[j];
                oz[512 + 5 * u + k] = wx * s;
            }
        }
    } else if (t < N0 + N1) {
        // ----- l1 = 1 block: instrs (1,0,1),(1,1,0),(1,1,1),(1,1,2),(1,2,1),(1,2,2) -----
        const int tt = t - N0;
        const int z = tt >> 6, u = tt & 63;
        const float* xz = x + (size_t)z * 480 + 128 + 3 * u;
        const float* yz = y + (size_t)z * 9;
        const float* wz = w + (size_t)z * 960;
        float* oz = out + (size_t)z * 3136;

        float xv[3];
#pragma unroll
        for (int i = 0; i < 3; ++i) xv[i] = xz[i];
        const float y0 = yz[0];
        float y1[3], y2[5];
#pragma unroll
        for (int j = 0; j < 3; ++j) y1[j] = yz[1 + j];
#pragma unroll
        for (int j = 0; j < 5; ++j) y2[j] = yz[4 + j];

        float xy1[3][3], xy2[3][5];
#pragma unroll
        for (int i = 0; i < 3; ++i) {
#pragma unroll
            for (int j = 0; j < 3; ++j) xy1[i][j] = xv[i] * y1[j];
#pragma unroll
            for (int j = 0; j < 5; ++j) xy2[i][j] = xv[i] * y2[j];
        }

        // (1,0,1) -> out[1152 + 3u + k], w[384+u]
        {
            const float wy = wz[384 + u] * y0;
#pragma unroll
            for (int k = 0; k < 3; ++k) {
                float s = 0.f;
#pragma unroll
                for (int i = 0; i < 3; ++i) s += P.c101[i * 3 + k] * xv[i];
                oz[1152 + 3 * u + k] = wy * s;
            }
        }
        // (1,1,0) -> out[1344 + u], w[448+u]
        {
            float s = 0.f;
#pragma unroll
            for (int i = 0; i < 3; ++i)
#pragma unroll
                for (int j = 0; j < 3; ++j) s += P.c110[i * 3 + j] * xy1[i][j];
            oz[1344 + u] = wz[448 + u] * s;
        }
        // (1,1,1) -> out[1408 + 3u + k], w[512+u]
        {
            const float wv = wz[512 + u];
#pragma unroll
            for (int k = 0; k < 3; ++k) {
                float s = 0.f;
#pragma unroll
                for (int i = 0; i < 3; ++i)
#pragma unroll
                    for (int j = 0; j < 3; ++j) s += P.c111[(i * 3 + j) * 3 + k] * xy1[i][j];
                oz[1408 + 3 * u + k] = wv * s;
            }
        }
        // (1,1,2) -> out[1600 + 5u + k], w[576+u]
        {
            const float wv = wz[576 + u];
#pragma unroll
            for (int k = 0; k < 5; ++k) {
                float s = 0.f;
#pragma unroll
                for (int i = 0; i < 3; ++i)
#pragma unroll
                    for (int j = 0; j < 3; ++j) s += P.c112[(i * 3 + j) * 5 + k] * xy1[i][j];
                oz[1600 + 5 * u + k] = wv * s;
            }
        }
        // (1,2,1) -> out[1920 + 3u + k], w[640+u]
        {
            const float wv = wz[640 + u];
#pragma unroll
            for (int k = 0; k < 3; ++k) {
                float s = 0.f;
#pragma unroll
                for (int i = 0; i < 3; ++i)
#pragma unroll
                    for (int j = 0; j < 5; ++j) s += P.c121[(i * 5 + j) * 3 + k] * xy2[i][j];
                oz[1920 + 3 * u + k] = wv * s;
            }
        }
        // (1,2,2) -> out[2112 + 5u + k], w[704+u]
        {
            const float wv = wz[704 + u];
#pragma unroll
            for (int k = 0; k < 5; ++k) {
                float s = 0.f;
#pragma unroll
                for (int i = 0; i < 3; ++i)
#pragma unroll
                    for (int j = 0; j < 5; ++j) s += P.c122[(i * 5 + j) * 5 + k] * xy2[i][j];
                oz[2112 + 5 * u + k] = wv * s;
            }
        }
    } else {
        // ----- l1 = 2 block: instrs (2,0,2),(2,1,1),(2,1,2),(2,2,0),(2,2,1),(2,2,2) -----
        const int tt = t - N0 - N1;
        if (tt >= Z * 32) return;
        const int z = tt >> 5, u = tt & 31;
        const float* xz = x + (size_t)z * 480 + 320 + 5 * u;
        const float* yz = y + (size_t)z * 9;
        const float* wz = w + (size_t)z * 960;
        float* oz = out + (size_t)z * 3136;

        float xv[5];
#pragma unroll
        for (int i = 0; i < 5; ++i) xv[i] = xz[i];
        const float y0 = yz[0];
        float y1[3], y2[5];
#pragma unroll
        for (int j = 0; j < 3; ++j) y1[j] = yz[1 + j];
#pragma unroll
        for (int j = 0; j < 5; ++j) y2[j] = yz[4 + j];

        float xy1[5][3], xy2[5][5];
#pragma unroll
        for (int i = 0; i < 5; ++i) {
#pragma unroll
            for (int j = 0; j < 3; ++j) xy1[i][j] = xv[i] * y1[j];
#pragma unroll
            for (int j = 0; j < 5; ++j) xy2[i][j] = xv[i] * y2[j];
        }

        // (2,0,2) -> out[2432 + 5u + k], w[768+u]
        {
            const float wy = wz[768 + u] * y0;
#pragma unroll
            for (int k = 0; k < 5; ++k) {
                float s = 0.f;
#pragma unroll
                for (int i = 0; i < 5; ++i) s += P.c202[i * 5 + k] * xv[i];
                oz[2432 + 5 * u + k] = wy * s;
            }
        }
        // (2,1,1) -> out[2592 + 3u + k], w[800+u]
        {
            const float wv = wz[800 + u];
#pragma unroll
            for (int k = 0; k < 3; ++k) {
                float s = 0.f;
#pragma unroll
                for (int i = 0; i < 5; ++i)
#pragma unroll
                    for (int j = 0; j < 3; ++j) s += P.c211[(i * 3 + j) * 3 + k] * xy1[i][j];
                oz[2592 + 3 * u + k] = wv * s;
            }
        }
        // (2,1,2) -> out[2688 + 5u + k], w[832+u]
        {
            const float wv = wz[832 + u];
#pragma unroll
            for (int k = 0; k < 5; ++k) {
                float s = 0.f;
#pragma unroll
                for (int i = 0; i < 5; ++i)
#pragma unroll
                    for (int j = 0; j < 3; ++j) s += P.c212[(i * 3 + j) * 5 + k] * xy1[i][j];
                oz[2688 + 5 * u + k] = wv * s;
            }
        }
        // (2,2,0) -> out[2848 + u], w[864+u]
        {
            float s = 0.f;
#pragma unroll
            for (int i = 0; i < 5; ++i)
#pragma unroll
                for (int j = 0; j < 5; ++j) s += P.c220[i * 5 + j] * xy2[i][j];
            oz[2848 + u] = wz[864 + u] * s;
        }
        // (2,2,1) -> out[2880 + 3u + k], w[896+u]
        {
            const float wv = wz[896 + u];
#pragma unroll
            for (int k = 0; k < 3; ++k) {
                float s = 0.f;
#pragma unroll
                for (int i = 0; i < 5; ++i)
#pragma unroll
                    for (int j = 0; j < 5; ++j) s += P.c221[(i * 5 + j) * 3 + k] * xy2[i][j];
                oz[2880 + 3 * u + k] = wv * s;
            }
        }
        // (2,2,2) -> out[2976 + 5u + k], w[928+u]
        {
            const float wv = wz[928 + u];
#pragma unroll
            for (int k = 0; k < 5; ++k) {
                float s = 0.f;
#pragma unroll
                for (int i = 0; i < 5; ++i)
#pragma unroll
                    for (int j = 0; j < 5; ++j) s += P.c222[(i * 5 + j) * 5 + k] * xy2[i][j];
                oz[2976 + 5 * u + k] = wv * s;
            }
        }
    }
}

extern "C" void kernel_launch(void* const* d_in, const int* in_sizes, int n_in,
                              void* d_out, int out_size, void* d_ws, size_t ws_size,
                              hipStream_t stream)
{
    const float* x = (const float*)d_in[0];
    const float* y = (const float*)d_in[1];
    const float* w = (const float*)d_in[2];
    float* out = (float*)d_out;

    const int Z = in_sizes[0] / 480;        // 50000
    const int total = Z * 224;              // one thread per (block,u,row) task
    const int grid = (total + 255) / 256;   // 43750 for Z=50000

    hipLaunchKernelGGL(dtp_kernel, dim3(grid), dim3(256), 0, stream,
                       x, y, w, out, g_pack, Z);
}

// Round 2
// 186.589 us; speedup vs baseline: 1.0273x; 1.0273x over previous
//
#include <hip/hip_runtime.h>
#include <cmath>
#include <complex>

// ---------------------------------------------------------------------------
// Wigner-3j (real basis, e3nn convention) computed on HOST in double precision,
// exactly replicating the reference's _su2_cg / _q_real_to_complex / _w3j.
// Path weight sqrt(2*l3+1) is folded into each tensor.
// Packed into a struct passed BY VALUE as a kernel argument (2460 bytes).
// ---------------------------------------------------------------------------

struct W3JPack {
    float c000[1];    // (0,0,0) 1*1*1
    float c011[9];    // (0,1,1) 1*3*3
    float c022[25];   // (0,2,2) 1*5*5
    float c101[9];    // (1,0,1) 3*1*3
    float c110[9];    // (1,1,0) 3*3*1
    float c111[27];   // (1,1,1)
    float c112[45];   // (1,1,2)
    float c121[45];   // (1,2,1)
    float c122[75];   // (1,2,2)
    float c202[25];   // (2,0,2)
    float c211[45];   // (2,1,1)
    float c212[75];   // (2,1,2)
    float c220[25];   // (2,2,0)
    float c221[75];   // (2,2,1)
    float c222[125];  // (2,2,2)
};

namespace {

using cd = std::complex<double>;

double factd(int n) { double r = 1.0; for (int i = 2; i <= n; ++i) r *= i; return r; }

double su2_cg(int j1, int j2, int j3, int m1, int m2, int m3) {
    if (m3 != m1 + m2) return 0.0;
    double pref = std::sqrt((2.0 * j3 + 1.0) * factd(j3 + j1 - j2) * factd(j3 - j1 + j2)
                            * factd(j1 + j2 - j3) / factd(j1 + j2 + j3 + 1));
    pref *= std::sqrt(factd(j3 + m3) * factd(j3 - m3) * factd(j1 - m1)
                      * factd(j1 + m1) * factd(j2 - m2) * factd(j2 + m2));
    int kmin = 0;
    if (j2 - j3 - m1 > kmin) kmin = j2 - j3 - m1;
    if (j1 - j3 + m2 > kmin) kmin = j1 - j3 + m2;
    int kmax = j1 + j2 - j3;
    if (j1 - m1 < kmax) kmax = j1 - m1;
    if (j2 + m2 < kmax) kmax = j2 + m2;
    double s = 0.0;
    for (int k = kmin; k <= kmax; ++k) {
        double den = factd(k) * factd(j1 + j2 - j3 - k) * factd(j1 - m1 - k)
                   * factd(j2 + m2 - k) * factd(j3 - j2 + m1 + k) * factd(j3 - j1 - m2 + k);
        s += ((k & 1) ? -1.0 : 1.0) / den;
    }
    return pref * s;
}

void qmat(int l, cd q[5][5]) {
    for (int a = 0; a < 5; ++a) for (int b = 0; b < 5; ++b) q[a][b] = cd(0, 0);
    const double is2 = 1.0 / std::sqrt(2.0);
    for (int m = -l; m < 0; ++m) {
        q[l + m][l - m] = cd(is2, 0.0);
        q[l + m][l + m] = cd(0.0, -is2);
    }
    q[l][l] = cd(1.0, 0.0);
    for (int m = 1; m <= l; ++m) {
        double sgn = (m & 1) ? -1.0 : 1.0;
        q[l + m][l + m] = cd(sgn * is2, 0.0);
        q[l + m][l - m] = cd(0.0, sgn * is2);
    }
    cd f(1.0, 0.0);
    const cd mi(0.0, -1.0);
    for (int k = 0; k < l; ++k) f *= mi;  // (-i)^l
    for (int a = 0; a < 5; ++a) for (int b = 0; b < 5; ++b) q[a][b] *= f;
}

void w3j_real(int l1, int l2, int l3, float* out, double pw) {
    const int d1 = 2 * l1 + 1, d2 = 2 * l2 + 1, d3 = 2 * l3 + 1;
    cd Q1[5][5], Q2[5][5], Q3[5][5];
    qmat(l1, Q1); qmat(l2, Q2); qmat(l3, Q3);
    double tmp[125];
    double norm2 = 0.0;
    for (int a = 0; a < d1; ++a)
        for (int b = 0; b < d2; ++b)
            for (int c = 0; c < d3; ++c) {
                cd acc(0.0, 0.0);
                for (int i = 0; i < d1; ++i) {
                    int m1 = i - l1;
                    for (int k = 0; k < d2; ++k) {
                        int m2 = k - l2;
                        int m3 = m1 + m2;
                        if (m3 < -l3 || m3 > l3) continue;
                        double cg = su2_cg(l1, l2, l3, m1, m2, m3);
                        if (cg == 0.0) continue;
                        acc += Q1[i][a] * Q2[k][b] * std::conj(Q3[m3 + l3][c]) * cg;
                    }
                }
                double v = acc.real();
                tmp[(a * d2 + b) * d3 + c] = v;
                norm2 += v * v;
            }
    const double scale = pw / std::sqrt(norm2);
    for (int idx = 0; idx < d1 * d2 * d3; ++idx) out[idx] = (float)(tmp[idx] * scale);
}

W3JPack build_pack() {
    W3JPack p;
    const double s3 = std::sqrt(3.0), s5 = std::sqrt(5.0);
    w3j_real(0, 0, 0, p.c000, 1.0);
    w3j_real(0, 1, 1, p.c011, s3);
    w3j_real(0, 2, 2, p.c022, s5);
    w3j_real(1, 0, 1, p.c101, s3);
    w3j_real(1, 1, 0, p.c110, 1.0);
    w3j_real(1, 1, 1, p.c111, s3);
    w3j_real(1, 1, 2, p.c112, s5);
    w3j_real(1, 2, 1, p.c121, s3);
    w3j_real(1, 2, 2, p.c122, s5);
    w3j_real(2, 0, 2, p.c202, s5);
    w3j_real(2, 1, 1, p.c211, s3);
    w3j_real(2, 1, 2, p.c212, s5);
    w3j_real(2, 2, 0, p.c220, 1.0);
    w3j_real(2, 2, 1, p.c221, s3);
    w3j_real(2, 2, 2, p.c222, s5);
    return p;
}

const W3JPack g_pack = build_pack();  // static init at library load; pure constants

// ---------------------------------------------------------------------------
// Intra-wave transpose-through-LDS helpers.
// Per-wave disjoint LDS regions; LDS ops within a wave complete in order, so
// only compiler-ordering fences (__builtin_amdgcn_wave_barrier) are needed.
// Write phase: lane ln writes K values at stride K (gcd(K,32)=1 for K=3,5 ->
// 2-way bank aliasing = free). Read/store phase: 64-lane contiguous dword
// runs, every span base 64B-aligned.
// ---------------------------------------------------------------------------

} // namespace

template<int K>
__device__ __forceinline__ void xchg_store(float* __restrict__ base,
                                           const float (&v)[K],
                                           float* __restrict__ buf, int ln)
{
#pragma unroll
    for (int k = 0; k < K; ++k) buf[K * ln + k] = v[k];
    __builtin_amdgcn_wave_barrier();
#pragma unroll
    for (int s = 0; s < K; ++s) base[64 * s + ln] = buf[64 * s + ln];
    __builtin_amdgcn_wave_barrier();
}

template<int K>
__device__ __forceinline__ void xchg_load(const float* __restrict__ base,
                                          float (&v)[K],
                                          float* __restrict__ buf, int ln)
{
#pragma unroll
    for (int s = 0; s < K; ++s) buf[64 * s + ln] = base[64 * s + ln];
    __builtin_amdgcn_wave_barrier();
#pragma unroll
    for (int k = 0; k < K; ++k) v[k] = buf[K * ln + k];
    __builtin_amdgcn_wave_barrier();
}

// Half-wave variants: lanes 0-31 / 32-63 target different rows (l1=2 block).
template<int K>
__device__ __forceinline__ void half_store(float* __restrict__ base_half,
                                           const float (&v)[K],
                                           float* __restrict__ buf, int li, int half)
{
    float* b = buf + half * K * 32;
#pragma unroll
    for (int k = 0; k < K; ++k) b[K * li + k] = v[k];
    __builtin_amdgcn_wave_barrier();
#pragma unroll
    for (int s = 0; s < K; ++s) base_half[32 * s + li] = b[32 * s + li];
    __builtin_amdgcn_wave_barrier();
}

template<int K>
__device__ __forceinline__ void half_load(const float* __restrict__ base_half,
                                          float (&v)[K],
                                          float* __restrict__ buf, int li, int half)
{
    float* b = buf + half * K * 32;
#pragma unroll
    for (int s = 0; s < K; ++s) b[32 * s + li] = base_half[32 * s + li];
    __builtin_amdgcn_wave_barrier();
#pragma unroll
    for (int k = 0; k < K; ++k) v[k] = b[K * li + k];
    __builtin_amdgcn_wave_barrier();
}

// ---------------------------------------------------------------------------
// One thread per (mul-block, u, row) task; all task-type boundaries are
// multiples of 64 so waves are branch-uniform.
// ---------------------------------------------------------------------------

__global__ __launch_bounds__(256) void dtp_kernel(
    const float* __restrict__ x, const float* __restrict__ y,
    const float* __restrict__ w, float* __restrict__ out,
    const W3JPack P, int Z)
{
    __shared__ float xch[4][320];
    const int ln = threadIdx.x & 63;
    float* buf = xch[threadIdx.x >> 6];

    const int t = blockIdx.x * 256 + threadIdx.x;
    const int N0 = Z * 128;
    const int N1 = Z * 64;

    if (t < N0) {
        // ----- l1 = 0: instrs (0,0,0),(0,1,1),(0,2,2); 128 u/row, wave = half row
        const int z = t >> 7, u = t & 127;
        const int u0 = u & ~63;                 // wave's u base (0 or 64)
        const float* xz = x + (size_t)z * 480;
        const float* yz = y + (size_t)z * 9;
        const float* wz = w + (size_t)z * 960;
        float* oz = out + (size_t)z * 3136;

        const float xv = xz[u];
        const float y0 = yz[0];
        float y1[3], y2[5];
#pragma unroll
        for (int j = 0; j < 3; ++j) y1[j] = yz[1 + j];
#pragma unroll
        for (int j = 0; j < 5; ++j) y2[j] = yz[4 + j];

        // (0,0,0): contiguous already
        oz[u] = wz[u] * (P.c000[0] * xv * y0);

        // (0,1,1)
        {
            const float wx = wz[128 + u] * xv;
            float o[3];
#pragma unroll
            for (int k = 0; k < 3; ++k) {
                float s = 0.f;
#pragma unroll
                for (int j = 0; j < 3; ++j) s += P.c011[j * 3 + k] * y1[j];
                o[k] = wx * s;
            }
            xchg_store<3>(oz + 128 + 3 * u0, o, buf, ln);
        }
        // (0,2,2)
        {
            const float wx = wz[256 + u] * xv;
            float o[5];
#pragma unroll
            for (int k = 0; k < 5; ++k) {
                float s = 0.f;
#pragma unroll
                for (int j = 0; j < 5; ++j) s += P.c022[j * 5 + k] * y2[j];
                o[k] = wx * s;
            }
            xchg_store<5>(oz + 512 + 5 * u0, o, buf, ln);
        }
    } else if (t < N0 + N1) {
        // ----- l1 = 1: 64 u/row, wave = one row (u == ln)
        const int tt = t - N0;
        const int z = tt >> 6;
        const int u = ln;
        const float* yz = y + (size_t)z * 9;
        const float* wz = w + (size_t)z * 960;
        float* oz = out + (size_t)z * 3136;

        float xv[3];
        xchg_load<3>(x + (size_t)z * 480 + 128, xv, buf, ln);

        const float y0 = yz[0];
        float y1[3], y2[5];
#pragma unroll
        for (int j = 0; j < 3; ++j) y1[j] = yz[1 + j];
#pragma unroll
        for (int j = 0; j < 5; ++j) y2[j] = yz[4 + j];

        float xy1[3][3], xy2[3][5];
#pragma unroll
        for (int i = 0; i < 3; ++i) {
#pragma unroll
            for (int j = 0; j < 3; ++j) xy1[i][j] = xv[i] * y1[j];
#pragma unroll
            for (int j = 0; j < 5; ++j) xy2[i][j] = xv[i] * y2[j];
        }

        // (1,0,1)
        {
            const float wy = wz[384 + u] * y0;
            float o[3];
#pragma unroll
            for (int k = 0; k < 3; ++k) {
                float s = 0.f;
#pragma unroll
                for (int i = 0; i < 3; ++i) s += P.c101[i * 3 + k] * xv[i];
                o[k] = wy * s;
            }
            xchg_store<3>(oz + 1152, o, buf, ln);
        }
        // (1,1,0): contiguous already
        {
            float s = 0.f;
#pragma unroll
            for (int i = 0; i < 3; ++i)
#pragma unroll
                for (int j = 0; j < 3; ++j) s += P.c110[i * 3 + j] * xy1[i][j];
            oz[1344 + u] = wz[448 + u] * s;
        }
        // (1,1,1)
        {
            const float wv = wz[512 + u];
            float o[3];
#pragma unroll
            for (int k = 0; k < 3; ++k) {
                float s = 0.f;
#pragma unroll
                for (int i = 0; i < 3; ++i)
#pragma unroll
                    for (int j = 0; j < 3; ++j) s += P.c111[(i * 3 + j) * 3 + k] * xy1[i][j];
                o[k] = wv * s;
            }
            xchg_store<3>(oz + 1408, o, buf, ln);
        }
        // (1,1,2)
        {
            const float wv = wz[576 + u];
            float o[5];
#pragma unroll
            for (int k = 0; k < 5; ++k) {
                float s = 0.f;
#pragma unroll
                for (int i = 0; i < 3; ++i)
#pragma unroll
                    for (int j = 0; j < 3; ++j) s += P.c112[(i * 3 + j) * 5 + k] * xy1[i][j];
                o[k] = wv * s;
            }
            xchg_store<5>(oz + 1600, o, buf, ln);
        }
        // (1,2,1)
        {
            const float wv = wz[640 + u];
            float o[3];
#pragma unroll
            for (int k = 0; k < 3; ++k) {
                float s = 0.f;
#pragma unroll
                for (int i = 0; i < 3; ++i)
#pragma unroll
                    for (int j = 0; j < 5; ++j) s += P.c121[(i * 5 + j) * 3 + k] * xy2[i][j];
                o[k] = wv * s;
            }
            xchg_store<3>(oz + 1920, o, buf, ln);
        }
        // (1,2,2)
        {
            const float wv = wz[704 + u];
            float o[5];
#pragma unroll
            for (int k = 0; k < 5; ++k) {
                float s = 0.f;
#pragma unroll
                for (int i = 0; i < 3; ++i)
#pragma unroll
                    for (int j = 0; j < 5; ++j) s += P.c122[(i * 5 + j) * 5 + k] * xy2[i][j];
                o[k] = wv * s;
            }
            xchg_store<5>(oz + 2112, o, buf, ln);
        }
    } else {
        // ----- l1 = 2: 32 u/row, wave = two rows (half-wave per row)
        const int tt = t - N0 - N1;
        if (tt >= Z * 32) return;
        const int z = tt >> 5;
        const int u = tt & 31;           // == li
        const int li = ln & 31, half = ln >> 5;
        const float* yz = y + (size_t)z * 9;
        const float* wz = w + (size_t)z * 960;
        float* oz = out + (size_t)z * 3136;

        float xv[5];
        half_load<5>(x + (size_t)z * 480 + 320, xv, buf, li, half);

        const float y0 = yz[0];
        float y1[3], y2[5];
#pragma unroll
        for (int j = 0; j < 3; ++j) y1[j] = yz[1 + j];
#pragma unroll
        for (int j = 0; j < 5; ++j) y2[j] = yz[4 + j];

        float xy1[5][3], xy2[5][5];
#pragma unroll
        for (int i = 0; i < 5; ++i) {
#pragma unroll
            for (int j = 0; j < 3; ++j) xy1[i][j] = xv[i] * y1[j];
#pragma unroll
            for (int j = 0; j < 5; ++j) xy2[i][j] = xv[i] * y2[j];
        }

        // (2,0,2)
        {
            const float wy = wz[768 + u] * y0;
            float o[5];
#pragma unroll
            for (int k = 0; k < 5; ++k) {
                float s = 0.f;
#pragma unroll
                for (int i = 0; i < 5; ++i) s += P.c202[i * 5 + k] * xv[i];
                o[k] = wy * s;
            }
            half_store<5>(oz + 2432, o, buf, li, half);
        }
        // (2,1,1)
        {
            const float wv = wz[800 + u];
            float o[3];
#pragma unroll
            for (int k = 0; k < 3; ++k) {
                float s = 0.f;
#pragma unroll
                for (int i = 0; i < 5; ++i)
#pragma unroll
                    for (int j = 0; j < 3; ++j) s += P.c211[(i * 3 + j) * 3 + k] * xy1[i][j];
                o[k] = wv * s;
            }
            half_store<3>(oz + 2592, o, buf, li, half);
        }
        // (2,1,2)
        {
            const float wv = wz[832 + u];
            float o[5];
#pragma unroll
            for (int k = 0; k < 5; ++k) {
                float s = 0.f;
#pragma unroll
                for (int i = 0; i < 5; ++i)
#pragma unroll
                    for (int j = 0; j < 3; ++j) s += P.c212[(i * 3 + j) * 5 + k] * xy1[i][j];
                o[k] = wv * s;
            }
            half_store<5>(oz + 2688, o, buf, li, half);
        }
        // (2,2,0): contiguous already (per half)
        {
            float s = 0.f;
#pragma unroll
            for (int i = 0; i < 5; ++i)
#pragma unroll
                for (int j = 0; j < 5; ++j) s += P.c220[i * 5 + j] * xy2[i][j];
            oz[2848 + u] = wz[864 + u] * s;
        }
        // (2,2,1)
        {
            const float wv = wz[896 + u];
            float o[3];
#pragma unroll
            for (int k = 0; k < 3; ++k) {
                float s = 0.f;
#pragma unroll
                for (int i = 0; i < 5; ++i)
#pragma unroll
                    for (int j = 0; j < 5; ++j) s += P.c221[(i * 5 + j) * 3 + k] * xy2[i][j];
                o[k] = wv * s;
            }
            half_store<3>(oz + 2880, o, buf, li, half);
        }
        // (2,2,2)
        {
            const float wv = wz[928 + u];
            float o[5];
#pragma unroll
            for (int k = 0; k < 5; ++k) {
                float s = 0.f;
#pragma unroll
                for (int i = 0; i < 5; ++i)
#pragma unroll
                    for (int j = 0; j < 5; ++j) s += P.c222[(i * 5 + j) * 5 + k] * xy2[i][j];
                o[k] = wv * s;
            }
            half_store<5>(oz + 2976, o, buf, li, half);
        }
    }
}

extern "C" void kernel_launch(void* const* d_in, const int* in_sizes, int n_in,
                              void* d_out, int out_size, void* d_ws, size_t ws_size,
                              hipStream_t stream)
{
    const float* x = (const float*)d_in[0];
    const float* y = (const float*)d_in[1];
    const float* w = (const float*)d_in[2];
    float* out = (float*)d_out;

    const int Z = in_sizes[0] / 480;        // 50000
    const int total = Z * 224;              // one thread per (block,u,row) task
    const int grid = (total + 255) / 256;   // 43750 for Z=50000

    hipLaunchKernelGGL(dtp_kernel, dim3(grid), dim3(256), 0, stream,
                       x, y, w, out, g_pack, Z);
}

// Round 3
// 166.914 us; speedup vs baseline: 1.1484x; 1.1179x over previous
//
#include <hip/hip_runtime.h>
#include <cmath>
#include <complex>

// ---------------------------------------------------------------------------
// Wigner-3j (real basis, e3nn convention) computed on HOST in double precision,
// exactly replicating the reference's _su2_cg / _q_real_to_complex / _w3j.
// Path weight sqrt(2*l3+1) is folded into each tensor.
// Packed into a struct passed BY VALUE as a kernel argument (2460 bytes).
// ---------------------------------------------------------------------------

struct W3JPack {
    float c000[1];    // (0,0,0)
    float c011[9];    // (0,1,1)
    float c022[25];   // (0,2,2)
    float c101[9];    // (1,0,1)
    float c110[9];    // (1,1,0)
    float c111[27];   // (1,1,1)
    float c112[45];   // (1,1,2)
    float c121[45];   // (1,2,1)
    float c122[75];   // (1,2,2)
    float c202[25];   // (2,0,2)
    float c211[45];   // (2,1,1)
    float c212[75];   // (2,1,2)
    float c220[25];   // (2,2,0)
    float c221[75];   // (2,2,1)
    float c222[125];  // (2,2,2)
};

namespace {

using cd = std::complex<double>;

double factd(int n) { double r = 1.0; for (int i = 2; i <= n; ++i) r *= i; return r; }

double su2_cg(int j1, int j2, int j3, int m1, int m2, int m3) {
    if (m3 != m1 + m2) return 0.0;
    double pref = std::sqrt((2.0 * j3 + 1.0) * factd(j3 + j1 - j2) * factd(j3 - j1 + j2)
                            * factd(j1 + j2 - j3) / factd(j1 + j2 + j3 + 1));
    pref *= std::sqrt(factd(j3 + m3) * factd(j3 - m3) * factd(j1 - m1)
                      * factd(j1 + m1) * factd(j2 - m2) * factd(j2 + m2));
    int kmin = 0;
    if (j2 - j3 - m1 > kmin) kmin = j2 - j3 - m1;
    if (j1 - j3 + m2 > kmin) kmin = j1 - j3 + m2;
    int kmax = j1 + j2 - j3;
    if (j1 - m1 < kmax) kmax = j1 - m1;
    if (j2 + m2 < kmax) kmax = j2 + m2;
    double s = 0.0;
    for (int k = kmin; k <= kmax; ++k) {
        double den = factd(k) * factd(j1 + j2 - j3 - k) * factd(j1 - m1 - k)
                   * factd(j2 + m2 - k) * factd(j3 - j2 + m1 + k) * factd(j3 - j1 - m2 + k);
        s += ((k & 1) ? -1.0 : 1.0) / den;
    }
    return pref * s;
}

void qmat(int l, cd q[5][5]) {
    for (int a = 0; a < 5; ++a) for (int b = 0; b < 5; ++b) q[a][b] = cd(0, 0);
    const double is2 = 1.0 / std::sqrt(2.0);
    for (int m = -l; m < 0; ++m) {
        q[l + m][l - m] = cd(is2, 0.0);
        q[l + m][l + m] = cd(0.0, -is2);
    }
    q[l][l] = cd(1.0, 0.0);
    for (int m = 1; m <= l; ++m) {
        double sgn = (m & 1) ? -1.0 : 1.0;
        q[l + m][l + m] = cd(sgn * is2, 0.0);
        q[l + m][l - m] = cd(0.0, sgn * is2);
    }
    cd f(1.0, 0.0);
    const cd mi(0.0, -1.0);
    for (int k = 0; k < l; ++k) f *= mi;  // (-i)^l
    for (int a = 0; a < 5; ++a) for (int b = 0; b < 5; ++b) q[a][b] *= f;
}

void w3j_real(int l1, int l2, int l3, float* out, double pw) {
    const int d1 = 2 * l1 + 1, d2 = 2 * l2 + 1, d3 = 2 * l3 + 1;
    cd Q1[5][5], Q2[5][5], Q3[5][5];
    qmat(l1, Q1); qmat(l2, Q2); qmat(l3, Q3);
    double tmp[125];
    double norm2 = 0.0;
    for (int a = 0; a < d1; ++a)
        for (int b = 0; b < d2; ++b)
            for (int c = 0; c < d3; ++c) {
                cd acc(0.0, 0.0);
                for (int i = 0; i < d1; ++i) {
                    int m1 = i - l1;
                    for (int k = 0; k < d2; ++k) {
                        int m2 = k - l2;
                        int m3 = m1 + m2;
                        if (m3 < -l3 || m3 > l3) continue;
                        double cg = su2_cg(l1, l2, l3, m1, m2, m3);
                        if (cg == 0.0) continue;
                        acc += Q1[i][a] * Q2[k][b] * std::conj(Q3[m3 + l3][c]) * cg;
                    }
                }
                double v = acc.real();
                tmp[(a * d2 + b) * d3 + c] = v;
                norm2 += v * v;
            }
    const double scale = pw / std::sqrt(norm2);
    for (int idx = 0; idx < d1 * d2 * d3; ++idx) out[idx] = (float)(tmp[idx] * scale);
}

W3JPack build_pack() {
    W3JPack p;
    const double s3 = std::sqrt(3.0), s5 = std::sqrt(5.0);
    w3j_real(0, 0, 0, p.c000, 1.0);
    w3j_real(0, 1, 1, p.c011, s3);
    w3j_real(0, 2, 2, p.c022, s5);
    w3j_real(1, 0, 1, p.c101, s3);
    w3j_real(1, 1, 0, p.c110, 1.0);
    w3j_real(1, 1, 1, p.c111, s3);
    w3j_real(1, 1, 2, p.c112, s5);
    w3j_real(1, 2, 1, p.c121, s3);
    w3j_real(1, 2, 2, p.c122, s5);
    w3j_real(2, 0, 2, p.c202, s5);
    w3j_real(2, 1, 1, p.c211, s3);
    w3j_real(2, 1, 2, p.c212, s5);
    w3j_real(2, 2, 0, p.c220, 1.0);
    w3j_real(2, 2, 1, p.c221, s3);
    w3j_real(2, 2, 2, p.c222, s5);
    return p;
}

const W3JPack g_pack = build_pack();  // static init at library load; pure constants

} // namespace

// ---------------------------------------------------------------------------
// One thread per (mul-block, u, row). Per-wave LDS staging of the wave's whole
// output span, then float4 (dwordx4) writeback. Wave-internal exchange only:
// per-wave disjoint LDS regions + wave_barrier (compiler fence; LDS ops within
// a wave complete in order). Block swizzle interleaves the three task phases
// 4:2:1 so write-heavy and VALU-heavy waves mix in time.
// ---------------------------------------------------------------------------

__global__ __launch_bounds__(256) void dtp_kernel(
    const float* __restrict__ x, const float* __restrict__ y,
    const float* __restrict__ w, float* __restrict__ out,
    const W3JPack P, int Z, int swz)
{
    __shared__ __align__(16) float xch[4][1408];
    const int tid = threadIdx.x;
    const int ln = tid & 63;
    float* buf = xch[tid >> 6];
    float4* bf4 = (float4*)buf;

    const int N0 = Z * 128;
    const int N1 = Z * 64;

    int t;
    if (swz) {
        const int bid = blockIdx.x;
        const int q = bid / 7, r = bid - 7 * q;   // 43750 = 7 * 6250, split 4:2:1
        if (r < 4)       t = (4 * q + r) * 256 + tid;
        else if (r < 6)  t = N0 + (2 * q + (r - 4)) * 256 + tid;
        else             t = N0 + N1 + q * 256 + tid;
    } else {
        t = blockIdx.x * 256 + tid;
        if (t >= Z * 224) return;
    }

    if (t < N0) {
        // ----- l1 = 0: (0,0,0),(0,1,1),(0,2,2); 128 u/row, wave = half row -----
        const int z = t >> 7, u = t & 127;
        const int u0 = u & 64;                       // wave's u base: 0 or 64
        const int zu = __builtin_amdgcn_readfirstlane(z);
        const float* xz = x + (size_t)zu * 480;
        const float* yz = y + (size_t)zu * 9;        // uniform -> s_load
        const float* wz = w + (size_t)zu * 960;
        float* oz = out + (size_t)zu * 3136;

        const float xv = xz[u];
        const float y0 = yz[0];
        float y1[3], y2[5];
#pragma unroll
        for (int j = 0; j < 3; ++j) y1[j] = yz[1 + j];
#pragma unroll
        for (int j = 0; j < 5; ++j) y2[j] = yz[4 + j];

        // stage into LDS: A[64] | B[192] | C[320]  (576 floats)
        buf[ln] = wz[u] * (P.c000[0] * xv * y0);
        {
            const float wx = wz[128 + u] * xv;
#pragma unroll
            for (int k = 0; k < 3; ++k) {
                float s = 0.f;
#pragma unroll
                for (int j = 0; j < 3; ++j) s += P.c011[j * 3 + k] * y1[j];
                buf[64 + 3 * ln + k] = wx * s;
            }
        }
        {
            const float wx = wz[256 + u] * xv;
#pragma unroll
            for (int k = 0; k < 5; ++k) {
                float s = 0.f;
#pragma unroll
                for (int j = 0; j < 5; ++j) s += P.c022[j * 5 + k] * y2[j];
                buf[256 + 5 * ln + k] = wx * s;
            }
        }
        __builtin_amdgcn_wave_barrier();
        // float4 writeback: spans A(16 f4), B(48 f4), C(80 f4)
        if (ln < 16) *(float4*)(oz + u0 + 4 * ln) = bf4[ln];
        if (ln < 48) *(float4*)(oz + 128 + 3 * u0 + 4 * ln) = bf4[16 + ln];
        *(float4*)(oz + 512 + 5 * u0 + 4 * ln) = bf4[64 + ln];
        if (ln < 16) *(float4*)(oz + 512 + 5 * u0 + 256 + 4 * ln) = bf4[128 + ln];
        __builtin_amdgcn_wave_barrier();
    } else if (t < N0 + N1) {
        // ----- l1 = 1: 64 u/row, wave = one row (u == ln) -----
        const int tt = t - N0;
        const int z = tt >> 6;
        const int u = ln;
        const int zu = __builtin_amdgcn_readfirstlane(z);
        const float* yz = y + (size_t)zu * 9;        // uniform -> s_load
        const float* wz = w + (size_t)zu * 960;
        float* oz = out + (size_t)zu * 3136;

        // x[128:320) = 192 floats, float4 staged
        {
            const float4* xs = (const float4*)(x + (size_t)zu * 480 + 128);
            if (ln < 48) *(float4*)(buf + 4 * ln) = xs[ln];
        }
        __builtin_amdgcn_wave_barrier();
        float xv[3];
#pragma unroll
        for (int i = 0; i < 3; ++i) xv[i] = buf[3 * ln + i];
        __builtin_amdgcn_wave_barrier();

        const float y0 = yz[0];
        float y1[3], y2[5];
#pragma unroll
        for (int j = 0; j < 3; ++j) y1[j] = yz[1 + j];
#pragma unroll
        for (int j = 0; j < 5; ++j) y2[j] = yz[4 + j];

        float xy1[3][3], xy2[3][5];
#pragma unroll
        for (int i = 0; i < 3; ++i) {
#pragma unroll
            for (int j = 0; j < 3; ++j) xy1[i][j] = xv[i] * y1[j];
#pragma unroll
            for (int j = 0; j < 5; ++j) xy2[i][j] = xv[i] * y2[j];
        }

        // stage 20 outputs/u into LDS at segment-relative offsets (base 1152):
        // (1,0,1)@0, (1,1,0)@192, (1,1,1)@256, (1,1,2)@448, (1,2,1)@768, (1,2,2)@960
        {
            const float wy = wz[384 + u] * y0;
#pragma unroll
            for (int k = 0; k < 3; ++k) {
                float s = 0.f;
#pragma unroll
                for (int i = 0; i < 3; ++i) s += P.c101[i * 3 + k] * xv[i];
                buf[3 * ln + k] = wy * s;
            }
        }
        {
            float s = 0.f;
#pragma unroll
            for (int i = 0; i < 3; ++i)
#pragma unroll
                for (int j = 0; j < 3; ++j) s += P.c110[i * 3 + j] * xy1[i][j];
            buf[192 + ln] = wz[448 + u] * s;
        }
        {
            const float wv = wz[512 + u];
#pragma unroll
            for (int k = 0; k < 3; ++k) {
                float s = 0.f;
#pragma unroll
                for (int i = 0; i < 3; ++i)
#pragma unroll
                    for (int j = 0; j < 3; ++j) s += P.c111[(i * 3 + j) * 3 + k] * xy1[i][j];
                buf[256 + 3 * ln + k] = wv * s;
            }
        }
        {
            const float wv = wz[576 + u];
#pragma unroll
            for (int k = 0; k < 5; ++k) {
                float s = 0.f;
#pragma unroll
                for (int i = 0; i < 3; ++i)
#pragma unroll
                    for (int j = 0; j < 3; ++j) s += P.c112[(i * 3 + j) * 5 + k] * xy1[i][j];
                buf[448 + 5 * ln + k] = wv * s;
            }
        }
        {
            const float wv = wz[640 + u];
#pragma unroll
            for (int k = 0; k < 3; ++k) {
                float s = 0.f;
#pragma unroll
                for (int i = 0; i < 3; ++i)
#pragma unroll
                    for (int j = 0; j < 5; ++j) s += P.c121[(i * 5 + j) * 3 + k] * xy2[i][j];
                buf[768 + 3 * ln + k] = wv * s;
            }
        }
        {
            const float wv = wz[704 + u];
#pragma unroll
            for (int k = 0; k < 5; ++k) {
                float s = 0.f;
#pragma unroll
                for (int i = 0; i < 3; ++i)
#pragma unroll
                    for (int j = 0; j < 5; ++j) s += P.c122[(i * 5 + j) * 5 + k] * xy2[i][j];
                buf[960 + 5 * ln + k] = wv * s;
            }
        }
        __builtin_amdgcn_wave_barrier();
        // contiguous out[1152:2432) = 320 f4
        float* ob = oz + 1152;
#pragma unroll
        for (int it = 0; it < 5; ++it)
            *(float4*)(ob + 4 * (it * 64 + ln)) = bf4[it * 64 + ln];
        __builtin_amdgcn_wave_barrier();
    } else {
        // ----- l1 = 2: 32 u/row, wave = two rows (half-wave per row) -----
        const int tt = t - N0 - N1;
        const int li = ln & 31, half = ln >> 5;
        const int z0 = __builtin_amdgcn_readfirstlane(tt >> 5);  // row of lanes 0-31
        const int z = z0 + half;                                 // per-lane row
        const int u = li;
        const float* yz = y + (size_t)z * 9;
        const float* wz = w + (size_t)z * 960;
        float* oz = out + (size_t)z * 3136;

        // x[320:480) = 160 floats/row, float4 staged per half: row h at buf[160h..]
        {
            const float4* xs = (const float4*)(x + (size_t)z * 480 + 320);
            *(float4*)(buf + 160 * half + 4 * li) = xs[li];
            if (li < 8) *(float4*)(buf + 160 * half + 128 + 4 * li) = xs[32 + li];
        }
        __builtin_amdgcn_wave_barrier();
        float xv[5];
#pragma unroll
        for (int i = 0; i < 5; ++i) xv[i] = buf[160 * half + 5 * li + i];
        __builtin_amdgcn_wave_barrier();

        const float y0 = yz[0];
        float y1[3], y2[5];
#pragma unroll
        for (int j = 0; j < 3; ++j) y1[j] = yz[1 + j];
#pragma unroll
        for (int j = 0; j < 5; ++j) y2[j] = yz[4 + j];

        float xy1[5][3], xy2[5][5];
#pragma unroll
        for (int i = 0; i < 5; ++i) {
#pragma unroll
            for (int j = 0; j < 3; ++j) xy1[i][j] = xv[i] * y1[j];
#pragma unroll
            for (int j = 0; j < 5; ++j) xy2[i][j] = xv[i] * y2[j];
        }

        // stage 22 outputs/u per half at buf[704*half + segrel] (base 2432):
        // (2,0,2)@0, (2,1,1)@160, (2,1,2)@256, (2,2,0)@416, (2,2,1)@448, (2,2,2)@544
        float* hb = buf + 704 * half;
        {
            const float wy = wz[768 + u] * y0;
#pragma unroll
            for (int k = 0; k < 5; ++k) {
                float s = 0.f;
#pragma unroll
                for (int i = 0; i < 5; ++i) s += P.c202[i * 5 + k] * xv[i];
                hb[5 * li + k] = wy * s;
            }
        }
        {
            const float wv = wz[800 + u];
#pragma unroll
            for (int k = 0; k < 3; ++k) {
                float s = 0.f;
#pragma unroll
                for (int i = 0; i < 5; ++i)
#pragma unroll
                    for (int j = 0; j < 3; ++j) s += P.c211[(i * 3 + j) * 3 + k] * xy1[i][j];
                hb[160 + 3 * li + k] = wv * s;
            }
        }
        {
            const float wv = wz[832 + u];
#pragma unroll
            for (int k = 0; k < 5; ++k) {
                float s = 0.f;
#pragma unroll
                for (int i = 0; i < 5; ++i)
#pragma unroll
                    for (int j = 0; j < 3; ++j) s += P.c212[(i * 3 + j) * 5 + k] * xy1[i][j];
                hb[256 + 5 * li + k] = wv * s;
            }
        }
        {
            float s = 0.f;
#pragma unroll
            for (int i = 0; i < 5; ++i)
#pragma unroll
                for (int j = 0; j < 5; ++j) s += P.c220[i * 5 + j] * xy2[i][j];
            hb[416 + li] = wz[864 + u] * s;
        }
        {
            const float wv = wz[896 + u];
#pragma unroll
            for (int k = 0; k < 3; ++k) {
                float s = 0.f;
#pragma unroll
                for (int i = 0; i < 5; ++i)
#pragma unroll
                    for (int j = 0; j < 5; ++j) s += P.c221[(i * 5 + j) * 3 + k] * xy2[i][j];
                hb[448 + 3 * li + k] = wv * s;
            }
        }
        {
            const float wv = wz[928 + u];
#pragma unroll
            for (int k = 0; k < 5; ++k) {
                float s = 0.f;
#pragma unroll
                for (int i = 0; i < 5; ++i)
#pragma unroll
                    for (int j = 0; j < 5; ++j) s += P.c222[(i * 5 + j) * 5 + k] * xy2[i][j];
                hb[544 + 5 * li + k] = wv * s;
            }
        }
        __builtin_amdgcn_wave_barrier();
        // contiguous out[2432:3136) = 176 f4 per row; both rows per wave
        float* ob = oz + 2432;
#pragma unroll
        for (int it = 0; it < 5; ++it)
            *(float4*)(ob + 4 * (it * 32 + li)) = *(float4*)(hb + 4 * (it * 32 + li));
        if (li < 16) *(float4*)(ob + 4 * (160 + li)) = *(float4*)(hb + 4 * (160 + li));
        __builtin_amdgcn_wave_barrier();
    }
}

extern "C" void kernel_launch(void* const* d_in, const int* in_sizes, int n_in,
                              void* d_out, int out_size, void* d_ws, size_t ws_size,
                              hipStream_t stream)
{
    const float* x = (const float*)d_in[0];
    const float* y = (const float*)d_in[1];
    const float* w = (const float*)d_in[2];
    float* out = (float*)d_out;

    const int Z = in_sizes[0] / 480;        // 50000
    const int total = Z * 224;
    const int grid = (total + 255) / 256;   // 43750 for Z=50000
    const int swz = (Z % 8 == 0) ? 1 : 0;   // exact 4:2:1 phase split needs Z%8==0

    hipLaunchKernelGGL(dtp_kernel, dim3(grid), dim3(256), 0, stream,
                       x, y, w, out, g_pack, Z, swz);
}

// Round 5
// 159.032 us; speedup vs baseline: 1.2053x; 1.0496x over previous
//
#include <hip/hip_runtime.h>
#include <cmath>
#include <complex>

// ---------------------------------------------------------------------------
// Wigner-3j (real basis, e3nn convention) computed on HOST in double precision,
// exactly replicating the reference's _su2_cg / _q_real_to_complex / _w3j.
// Path weight sqrt(2*l3+1) is folded into each tensor.
// Packed into a struct passed BY VALUE as a kernel argument (2460 bytes).
// ---------------------------------------------------------------------------

struct W3JPack {
    float c000[1];    // (0,0,0)
    float c011[9];    // (0,1,1)
    float c022[25];   // (0,2,2)
    float c101[9];    // (1,0,1)
    float c110[9];    // (1,1,0)
    float c111[27];   // (1,1,1)
    float c112[45];   // (1,1,2)
    float c121[45];   // (1,2,1)
    float c122[75];   // (1,2,2)
    float c202[25];   // (2,0,2)
    float c211[45];   // (2,1,1)
    float c212[75];   // (2,1,2)
    float c220[25];   // (2,2,0)
    float c221[75];   // (2,2,1)
    float c222[125];  // (2,2,2)
};

namespace {

using cd = std::complex<double>;

double factd(int n) { double r = 1.0; for (int i = 2; i <= n; ++i) r *= i; return r; }

double su2_cg(int j1, int j2, int j3, int m1, int m2, int m3) {
    if (m3 != m1 + m2) return 0.0;
    double pref = std::sqrt((2.0 * j3 + 1.0) * factd(j3 + j1 - j2) * factd(j3 - j1 + j2)
                            * factd(j1 + j2 - j3) / factd(j1 + j2 + j3 + 1));
    pref *= std::sqrt(factd(j3 + m3) * factd(j3 - m3) * factd(j1 - m1)
                      * factd(j1 + m1) * factd(j2 - m2) * factd(j2 + m2));
    int kmin = 0;
    if (j2 - j3 - m1 > kmin) kmin = j2 - j3 - m1;
    if (j1 - j3 + m2 > kmin) kmin = j1 - j3 + m2;
    int kmax = j1 + j2 - j3;
    if (j1 - m1 < kmax) kmax = j1 - m1;
    if (j2 + m2 < kmax) kmax = j2 + m2;
    double s = 0.0;
    for (int k = kmin; k <= kmax; ++k) {
        double den = factd(k) * factd(j1 + j2 - j3 - k) * factd(j1 - m1 - k)
                   * factd(j2 + m2 - k) * factd(j3 - j2 + m1 + k) * factd(j3 - j1 - m2 + k);
        s += ((k & 1) ? -1.0 : 1.0) / den;
    }
    return pref * s;
}

void qmat(int l, cd q[5][5]) {
    for (int a = 0; a < 5; ++a) for (int b = 0; b < 5; ++b) q[a][b] = cd(0, 0);
    const double is2 = 1.0 / std::sqrt(2.0);
    for (int m = -l; m < 0; ++m) {
        q[l + m][l - m] = cd(is2, 0.0);
        q[l + m][l + m] = cd(0.0, -is2);
    }
    q[l][l] = cd(1.0, 0.0);
    for (int m = 1; m <= l; ++m) {
        double sgn = (m & 1) ? -1.0 : 1.0;
        q[l + m][l + m] = cd(sgn * is2, 0.0);
        q[l + m][l - m] = cd(0.0, sgn * is2);
    }
    cd f(1.0, 0.0);
    const cd mi(0.0, -1.0);
    for (int k = 0; k < l; ++k) f *= mi;  // (-i)^l
    for (int a = 0; a < 5; ++a) for (int b = 0; b < 5; ++b) q[a][b] *= f;
}

void w3j_real(int l1, int l2, int l3, float* out, double pw) {
    const int d1 = 2 * l1 + 1, d2 = 2 * l2 + 1, d3 = 2 * l3 + 1;
    cd Q1[5][5], Q2[5][5], Q3[5][5];
    qmat(l1, Q1); qmat(l2, Q2); qmat(l3, Q3);
    double tmp[125];
    double norm2 = 0.0;
    for (int a = 0; a < d1; ++a)
        for (int b = 0; b < d2; ++b)
            for (int c = 0; c < d3; ++c) {
                cd acc(0.0, 0.0);
                for (int i = 0; i < d1; ++i) {
                    int m1 = i - l1;
                    for (int k = 0; k < d2; ++k) {
                        int m2 = k - l2;
                        int m3 = m1 + m2;
                        if (m3 < -l3 || m3 > l3) continue;
                        double cg = su2_cg(l1, l2, l3, m1, m2, m3);
                        if (cg == 0.0) continue;
                        acc += Q1[i][a] * Q2[k][b] * std::conj(Q3[m3 + l3][c]) * cg;
                    }
                }
                double v = acc.real();
                tmp[(a * d2 + b) * d3 + c] = v;
                norm2 += v * v;
            }
    const double scale = pw / std::sqrt(norm2);
    for (int idx = 0; idx < d1 * d2 * d3; ++idx) out[idx] = (float)(tmp[idx] * scale);
}

W3JPack build_pack() {
    W3JPack p;
    const double s3 = std::sqrt(3.0), s5 = std::sqrt(5.0);
    w3j_real(0, 0, 0, p.c000, 1.0);
    w3j_real(0, 1, 1, p.c011, s3);
    w3j_real(0, 2, 2, p.c022, s5);
    w3j_real(1, 0, 1, p.c101, s3);
    w3j_real(1, 1, 0, p.c110, 1.0);
    w3j_real(1, 1, 1, p.c111, s3);
    w3j_real(1, 1, 2, p.c112, s5);
    w3j_real(1, 2, 1, p.c121, s3);
    w3j_real(1, 2, 2, p.c122, s5);
    w3j_real(2, 0, 2, p.c202, s5);
    w3j_real(2, 1, 1, p.c211, s3);
    w3j_real(2, 1, 2, p.c212, s5);
    w3j_real(2, 2, 0, p.c220, 1.0);
    w3j_real(2, 2, 1, p.c221, s3);
    w3j_real(2, 2, 2, p.c222, s5);
    return p;
}

const W3JPack g_pack = build_pack();  // static init at library load; pure constants

} // namespace

// Native clang vector (ext_vector_type) — required by the nontemporal builtins,
// which reject HIP's class-type float4. Bit-compatible with 4 packed floats.
typedef float f32x4 __attribute__((ext_vector_type(4)));

__device__ __forceinline__ float ntl(const float* p) {
    return __builtin_nontemporal_load(p);
}
__device__ __forceinline__ f32x4 ntl4(const float* p) {
    return __builtin_nontemporal_load((const f32x4*)p);
}
__device__ __forceinline__ void nts4(float* p, f32x4 v) {
    __builtin_nontemporal_store(v, (f32x4*)p);
}

// ---------------------------------------------------------------------------
// One thread per (mul-block, u, row). Per-wave LDS staging of the wave's whole
// output span, then nontemporal float4 writeback. Wave-internal exchange only:
// per-wave disjoint LDS regions + wave_barrier (compiler fence; LDS ops within
// a wave complete in order). Block swizzle interleaves the three task phases
// 4:2:1 so write-heavy and VALU-heavy waves mix in time.
// ---------------------------------------------------------------------------

__global__ __launch_bounds__(256) void dtp_kernel(
    const float* __restrict__ x, const float* __restrict__ y,
    const float* __restrict__ w, float* __restrict__ out,
    const W3JPack P, int Z, int swz)
{
    __shared__ __align__(16) float xch[4][1408];
    const int tid = threadIdx.x;
    const int ln = tid & 63;
    float* buf = xch[tid >> 6];
    f32x4* bf4 = (f32x4*)buf;

    const int N0 = Z * 128;
    const int N1 = Z * 64;

    int t;
    if (swz) {
        const int bid = blockIdx.x;
        const int q = bid / 7, r = bid - 7 * q;   // 43750 = 7 * 6250, split 4:2:1
        if (r < 4)       t = (4 * q + r) * 256 + tid;
        else if (r < 6)  t = N0 + (2 * q + (r - 4)) * 256 + tid;
        else             t = N0 + N1 + q * 256 + tid;
    } else {
        t = blockIdx.x * 256 + tid;
        if (t >= Z * 224) return;
    }

    if (t < N0) {
        // ----- l1 = 0: (0,0,0),(0,1,1),(0,2,2); 128 u/row, wave = half row -----
        const int z = t >> 7, u = t & 127;
        const int u0 = u & 64;                       // wave's u base: 0 or 64
        const int zu = __builtin_amdgcn_readfirstlane(z);
        const float* xz = x + (size_t)zu * 480;
        const float* yz = y + (size_t)zu * 9;        // uniform -> s_load
        const float* wz = w + (size_t)zu * 960;
        float* oz = out + (size_t)zu * 3136;

        const float xv = ntl(xz + u);
        const float y0 = yz[0];
        float y1[3], y2[5];
#pragma unroll
        for (int j = 0; j < 3; ++j) y1[j] = yz[1 + j];
#pragma unroll
        for (int j = 0; j < 5; ++j) y2[j] = yz[4 + j];

        // stage into LDS: A[64] | B[192] | C[320]  (576 floats)
        buf[ln] = ntl(wz + u) * (P.c000[0] * xv * y0);
        {
            const float wx = ntl(wz + 128 + u) * xv;
#pragma unroll
            for (int k = 0; k < 3; ++k) {
                float s = 0.f;
#pragma unroll
                for (int j = 0; j < 3; ++j) s += P.c011[j * 3 + k] * y1[j];
                buf[64 + 3 * ln + k] = wx * s;
            }
        }
        {
            const float wx = ntl(wz + 256 + u) * xv;
#pragma unroll
            for (int k = 0; k < 5; ++k) {
                float s = 0.f;
#pragma unroll
                for (int j = 0; j < 5; ++j) s += P.c022[j * 5 + k] * y2[j];
                buf[256 + 5 * ln + k] = wx * s;
            }
        }
        __builtin_amdgcn_wave_barrier();
        // float4 writeback: spans A(16 f4), B(48 f4), C(80 f4)
        if (ln < 16) nts4(oz + u0 + 4 * ln, bf4[ln]);
        if (ln < 48) nts4(oz + 128 + 3 * u0 + 4 * ln, bf4[16 + ln]);
        nts4(oz + 512 + 5 * u0 + 4 * ln, bf4[64 + ln]);
        if (ln < 16) nts4(oz + 512 + 5 * u0 + 256 + 4 * ln, bf4[128 + ln]);
        __builtin_amdgcn_wave_barrier();
    } else if (t < N0 + N1) {
        // ----- l1 = 1: 64 u/row, wave = one row (u == ln) -----
        const int tt = t - N0;
        const int z = tt >> 6;
        const int u = ln;
        const int zu = __builtin_amdgcn_readfirstlane(z);
        const float* yz = y + (size_t)zu * 9;        // uniform -> s_load
        const float* wz = w + (size_t)zu * 960;
        float* oz = out + (size_t)zu * 3136;

        // x[128:320) = 192 floats, float4 staged
        {
            const float* xs = x + (size_t)zu * 480 + 128;
            if (ln < 48) bf4[ln] = ntl4(xs + 4 * ln);
        }
        __builtin_amdgcn_wave_barrier();
        float xv[3];
#pragma unroll
        for (int i = 0; i < 3; ++i) xv[i] = buf[3 * ln + i];
        __builtin_amdgcn_wave_barrier();

        const float y0 = yz[0];
        float y1[3], y2[5];
#pragma unroll
        for (int j = 0; j < 3; ++j) y1[j] = yz[1 + j];
#pragma unroll
        for (int j = 0; j < 5; ++j) y2[j] = yz[4 + j];

        float xy1[3][3], xy2[3][5];
#pragma unroll
        for (int i = 0; i < 3; ++i) {
#pragma unroll
            for (int j = 0; j < 3; ++j) xy1[i][j] = xv[i] * y1[j];
#pragma unroll
            for (int j = 0; j < 5; ++j) xy2[i][j] = xv[i] * y2[j];
        }

        // stage 20 outputs/u into LDS at segment-relative offsets (base 1152):
        // (1,0,1)@0, (1,1,0)@192, (1,1,1)@256, (1,1,2)@448, (1,2,1)@768, (1,2,2)@960
        {
            const float wy = ntl(wz + 384 + u) * y0;
#pragma unroll
            for (int k = 0; k < 3; ++k) {
                float s = 0.f;
#pragma unroll
                for (int i = 0; i < 3; ++i) s += P.c101[i * 3 + k] * xv[i];
                buf[3 * ln + k] = wy * s;
            }
        }
        {
            float s = 0.f;
#pragma unroll
            for (int i = 0; i < 3; ++i)
#pragma unroll
                for (int j = 0; j < 3; ++j) s += P.c110[i * 3 + j] * xy1[i][j];
            buf[192 + ln] = ntl(wz + 448 + u) * s;
        }
        {
            const float wv = ntl(wz + 512 + u);
#pragma unroll
            for (int k = 0; k < 3; ++k) {
                float s = 0.f;
#pragma unroll
                for (int i = 0; i < 3; ++i)
#pragma unroll
                    for (int j = 0; j < 3; ++j) s += P.c111[(i * 3 + j) * 3 + k] * xy1[i][j];
                buf[256 + 3 * ln + k] = wv * s;
            }
        }
        {
            const float wv = ntl(wz + 576 + u);
#pragma unroll
            for (int k = 0; k < 5; ++k) {
                float s = 0.f;
#pragma unroll
                for (int i = 0; i < 3; ++i)
#pragma unroll
                    for (int j = 0; j < 3; ++j) s += P.c112[(i * 3 + j) * 5 + k] * xy1[i][j];
                buf[448 + 5 * ln + k] = wv * s;
            }
        }
        {
            const float wv = ntl(wz + 640 + u);
#pragma unroll
            for (int k = 0; k < 3; ++k) {
                float s = 0.f;
#pragma unroll
                for (int i = 0; i < 3; ++i)
#pragma unroll
                    for (int j = 0; j < 5; ++j) s += P.c121[(i * 5 + j) * 3 + k] * xy2[i][j];
                buf[768 + 3 * ln + k] = wv * s;
            }
        }
        {
            const float wv = ntl(wz + 704 + u);
#pragma unroll
            for (int k = 0; k < 5; ++k) {
                float s = 0.f;
#pragma unroll
                for (int i = 0; i < 3; ++i)
#pragma unroll
                    for (int j = 0; j < 5; ++j) s += P.c122[(i * 5 + j) * 5 + k] * xy2[i][j];
                buf[960 + 5 * ln + k] = wv * s;
            }
        }
        __builtin_amdgcn_wave_barrier();
        // contiguous out[1152:2432) = 320 f4
        float* ob = oz + 1152;
#pragma unroll
        for (int it = 0; it < 5; ++it)
            nts4(ob + 4 * (it * 64 + ln), bf4[it * 64 + ln]);
        __builtin_amdgcn_wave_barrier();
    } else {
        // ----- l1 = 2: 32 u/row, wave = two rows (half-wave per row) -----
        const int tt = t - N0 - N1;
        const int li = ln & 31, half = ln >> 5;
        const int z0 = __builtin_amdgcn_readfirstlane(tt >> 5);  // row of lanes 0-31
        const int z = z0 + half;                                 // per-lane row
        const int u = li;
        const float* wz = w + (size_t)z * 960;
        float* oz = out + (size_t)z * 3136;

        // y for both rows via wave-uniform scalar loads + per-lane select
        // (removes 9 per-lane VMEM loads from the VALU-heaviest phase)
        const float* yz0 = y + (size_t)z0 * 9;   // uniform -> s_load; [0:9)=row z0, [9:18)=row z0+1
        float y0v, y1[3], y2[5];
        {
            float ya[9], yb[9];
#pragma unroll
            for (int j = 0; j < 9; ++j) { ya[j] = yz0[j]; yb[j] = yz0[9 + j]; }
            y0v = half ? yb[0] : ya[0];
#pragma unroll
            for (int j = 0; j < 3; ++j) y1[j] = half ? yb[1 + j] : ya[1 + j];
#pragma unroll
            for (int j = 0; j < 5; ++j) y2[j] = half ? yb[4 + j] : ya[4 + j];
        }

        // x[320:480) = 160 floats/row, float4 staged per half: row h at buf[160h..]
        {
            const float* xs = x + (size_t)z * 480 + 320;
            *(f32x4*)(buf + 160 * half + 4 * li) = ntl4(xs + 4 * li);
            if (li < 8) *(f32x4*)(buf + 160 * half + 128 + 4 * li) = ntl4(xs + 128 + 4 * li);
        }
        __builtin_amdgcn_wave_barrier();
        float xv[5];
#pragma unroll
        for (int i = 0; i < 5; ++i) xv[i] = buf[160 * half + 5 * li + i];
        __builtin_amdgcn_wave_barrier();

        float xy1[5][3], xy2[5][5];
#pragma unroll
        for (int i = 0; i < 5; ++i) {
#pragma unroll
            for (int j = 0; j < 3; ++j) xy1[i][j] = xv[i] * y1[j];
#pragma unroll
            for (int j = 0; j < 5; ++j) xy2[i][j] = xv[i] * y2[j];
        }

        // stage 22 outputs/u per half at buf[704*half + segrel] (base 2432):
        // (2,0,2)@0, (2,1,1)@160, (2,1,2)@256, (2,2,0)@416, (2,2,1)@448, (2,2,2)@544
        float* hb = buf + 704 * half;
        {
            const float wy = ntl(wz + 768 + u) * y0v;
#pragma unroll
            for (int k = 0; k < 5; ++k) {
                float s = 0.f;
#pragma unroll
                for (int i = 0; i < 5; ++i) s += P.c202[i * 5 + k] * xv[i];
                hb[5 * li + k] = wy * s;
            }
        }
        {
            const float wv = ntl(wz + 800 + u);
#pragma unroll
            for (int k = 0; k < 3; ++k) {
                float s = 0.f;
#pragma unroll
                for (int i = 0; i < 5; ++i)
#pragma unroll
                    for (int j = 0; j < 3; ++j) s += P.c211[(i * 3 + j) * 3 + k] * xy1[i][j];
                hb[160 + 3 * li + k] = wv * s;
            }
        }
        {
            const float wv = ntl(wz + 832 + u);
#pragma unroll
            for (int k = 0; k < 5; ++k) {
                float s = 0.f;
#pragma unroll
                for (int i = 0; i < 5; ++i)
#pragma unroll
                    for (int j = 0; j < 3; ++j) s += P.c212[(i * 3 + j) * 5 + k] * xy1[i][j];
                hb[256 + 5 * li + k] = wv * s;
            }
        }
        {
            float s = 0.f;
#pragma unroll
            for (int i = 0; i < 5; ++i)
#pragma unroll
                for (int j = 0; j < 5; ++j) s += P.c220[i * 5 + j] * xy2[i][j];
            hb[416 + li] = ntl(wz + 864 + u) * s;
        }
        {
            const float wv = ntl(wz + 896 + u);
#pragma unroll
            for (int k = 0; k < 3; ++k) {
                float s = 0.f;
#pragma unroll
                for (int i = 0; i < 5; ++i)
#pragma unroll
                    for (int j = 0; j < 5; ++j) s += P.c221[(i * 5 + j) * 3 + k] * xy2[i][j];
                hb[448 + 3 * li + k] = wv * s;
            }
        }
        {
            const float wv = ntl(wz + 928 + u);
#pragma unroll
            for (int k = 0; k < 5; ++k) {
                float s = 0.f;
#pragma unroll
                for (int i = 0; i < 5; ++i)
#pragma unroll
                    for (int j = 0; j < 5; ++j) s += P.c222[(i * 5 + j) * 5 + k] * xy2[i][j];
                hb[544 + 5 * li + k] = wv * s;
            }
        }
        __builtin_amdgcn_wave_barrier();
        // contiguous out[2432:3136) = 176 f4 per row; both rows per wave
        float* ob = oz + 2432;
#pragma unroll
        for (int it = 0; it < 5; ++it)
            nts4(ob + 4 * (it * 32 + li), *(f32x4*)(hb + 4 * (it * 32 + li)));
        if (li < 16) nts4(ob + 4 * (160 + li), *(f32x4*)(hb + 4 * (160 + li)));
        __builtin_amdgcn_wave_barrier();
    }
}

extern "C" void kernel_launch(void* const* d_in, const int* in_sizes, int n_in,
                              void* d_out, int out_size, void* d_ws, size_t ws_size,
                              hipStream_t stream)
{
    const float* x = (const float*)d_in[0];
    const float* y = (const float*)d_in[1];
    const float* w = (const float*)d_in[2];
    float* out = (float*)d_out;

    const int Z = in_sizes[0] / 480;        // 50000
    const int total = Z * 224;
    const int grid = (total + 255) / 256;   // 43750 for Z=50000
    const int swz = (Z % 8 == 0) ? 1 : 0;   // exact 4:2:1 phase split needs Z%8==0

    hipLaunchKernelGGL(dtp_kernel, dim3(grid), dim3(256), 0, stream,
                       x, y, w, out, g_pack, Z, swz);
}